// Round 1
// baseline (301.367 us; speedup 1.0000x reference)
//
#include <hip/hip_runtime.h>
#include <math.h>

#define NCLS 5
#define NBINS 25
#define NTHREADS 256
#define NBLOCKS 2048
#define CHUNK_ROWS 1024                      // rows per LDS chunk
#define CHUNK_FLOATS (CHUNK_ROWS * NCLS)     // 5120 floats = 20480 B
#define CHUNK_F4 (CHUNK_FLOATS / 4)          // 1280 float4
#define ISSUES_PER_WAVE 5                    // 1280 f4 / 4 waves / 64 lanes

// global -> LDS direct copy, 16B per lane. LDS dest must be the wave-uniform
// base (HW adds lane*16); global src is per-lane.
__device__ __forceinline__ void gload_lds16(const void* g, void* l) {
    __builtin_amdgcn_global_load_lds(
        (const __attribute__((address_space(1))) unsigned int*)(const unsigned int*)g,
        (__attribute__((address_space(3))) unsigned int*)(unsigned int*)l,
        16, 0, 0);
}

// Kernel 1: double-buffered LDS-staged streaming.
// Per chunk: 20 coalesced global_load_lds (1KB/wave-instr), counted vmcnt(5)
// so the next chunk's prefetch stays in flight across the barrier.
// Round-robin row ownership (row = tid + 256*rr) makes the LDS image linear
// (global_load_lds requirement) AND makes row reads conflict-free:
// float idx = (tid + 256*rr)*5 + c -> bank = (5*lane + const) % 32, gcd(5,32)=1.
__global__ void __launch_bounds__(NTHREADS)
kappa_count(const float* __restrict__ preds,
            const int* __restrict__ truev,
            int N,
            unsigned int* __restrict__ partials) {
    __shared__ float s_stage[2][CHUNK_FLOATS];   // 40 KiB
    __shared__ unsigned int s_conf[4 * 32];      // per-wave histogram copies

    const int tid = threadIdx.x;
    const int wv = tid >> 6;
    const int lane = tid & 63;

    if (tid < 128) s_conf[tid] = 0u;
    __syncthreads();

    const int nchunks = N / CHUNK_ROWS;
    const int G = gridDim.x;

    auto stage = [&](int c, int b) {
        const float4* src = (const float4*)preds + (size_t)c * CHUNK_F4;
        #pragma unroll
        for (int k = 0; k < ISSUES_PER_WAVE; ++k) {
            const int seg = wv * ISSUES_PER_WAVE + k;        // 0..19
            gload_lds16(src + seg * 64 + lane,               // per-lane 16B src
                        &s_stage[b][seg * 256]);             // uniform 1KB seg base
        }
    };

    unsigned int* hist = &s_conf[wv << 5];

    int c = (int)blockIdx.x;
    int cur = 0;
    if (c < nchunks) stage(c, 0);

    for (; c < nchunks; c += G) {
        const int cn = c + G;
        if (cn < nchunks) {
            stage(cn, cur ^ 1);
            // wait everything except the 5 next-chunk loads just issued
            asm volatile("s_waitcnt vmcnt(5)" ::: "memory");
        } else {
            asm volatile("s_waitcnt vmcnt(0)" ::: "memory");
        }
        __builtin_amdgcn_s_barrier();          // buf[cur] visible to all waves
        asm volatile("" ::: "memory");

        const int rbase = c * CHUNK_ROWS;
        int ts[4];
        #pragma unroll
        for (int rr = 0; rr < 4; ++rr) ts[rr] = truev[rbase + tid + (rr << 8)];

        const float* bufp = s_stage[cur];
        #pragma unroll
        for (int rr = 0; rr < 4; ++rr) {
            const float* rp = bufp + (tid + (rr << 8)) * NCLS;
            float r0 = rp[0], r1 = rp[1], r2 = rp[2], r3 = rp[3], r4 = rp[4];
            // arithmetic kept expression-identical to the verified kernel
            float m = fmaxf(fmaxf(fmaxf(fmaxf(r0, r1), r2), r3), r4);
            float e0 = __expf(r0 - m), e1 = __expf(r1 - m), e2 = __expf(r2 - m),
                  e3 = __expf(r3 - m), e4 = __expf(r4 - m);
            float s = e0 + e1 + e2 + e3 + e4;
            float dot = e1 + e2 * 2.f + e3 * 3.f + e4 * 4.f;
            int pi = (int)rintf(dot / s);      // round-half-even == jnp.round
            pi = min(max(pi, 0), NCLS - 1);
            atomicAdd(&hist[ts[rr] * NCLS + pi], 1u);
        }
        asm volatile("" ::: "memory");
        __builtin_amdgcn_s_barrier();          // all reads of buf[cur] done
        cur ^= 1;
    }

    // tail rows (N % CHUNK_ROWS): block 0, direct from global (tiny)
    if (blockIdx.x == 0) {
        for (int r = nchunks * CHUNK_ROWS + tid; r < N; r += NTHREADS) {
            float v0 = preds[(size_t)r * NCLS + 0];
            float v1 = preds[(size_t)r * NCLS + 1];
            float v2 = preds[(size_t)r * NCLS + 2];
            float v3 = preds[(size_t)r * NCLS + 3];
            float v4 = preds[(size_t)r * NCLS + 4];
            float m = fmaxf(fmaxf(fmaxf(fmaxf(v0, v1), v2), v3), v4);
            float e0 = __expf(v0 - m), e1 = __expf(v1 - m), e2 = __expf(v2 - m),
                  e3 = __expf(v3 - m), e4 = __expf(v4 - m);
            float s = e0 + e1 + e2 + e3 + e4;
            float dot = e1 + e2 * 2.f + e3 * 3.f + e4 * 4.f;
            int pi = (int)rintf(dot / s);
            pi = min(max(pi, 0), NCLS - 1);
            atomicAdd(&hist[truev[r] * NCLS + pi], 1u);
        }
    }

    __syncthreads();
    if (tid < NBINS)
        partials[blockIdx.x * NBINS + tid] =
            s_conf[tid] + s_conf[32 + tid] + s_conf[64 + tid] + s_conf[96 + tid];
}

// Kernel 2: reduce per-block partials, O(25) kappa math in double.
__global__ void kappa_final(const unsigned int* __restrict__ partials,
                            int nblocks,
                            float* __restrict__ out) {
    __shared__ unsigned int s_conf[NBINS];
    const int tid = threadIdx.x;
    if (tid < NBINS) s_conf[tid] = 0u;
    __syncthreads();

    const int total = nblocks * NBINS;
    for (int i = tid; i < total; i += blockDim.x) {
        unsigned int v = partials[i];
        if (v) atomicAdd(&s_conf[i % NBINS], v);
    }
    __syncthreads();

    if (tid == 0) {
        double conf[NBINS];
        double tot = 0.0;
        for (int i = 0; i < NBINS; i++) { conf[i] = (double)s_conf[i]; tot += conf[i]; }
        double th[NCLS] = {0, 0, 0, 0, 0};
        double ph[NCLS] = {0, 0, 0, 0, 0};
        for (int i = 0; i < NCLS; i++)
            for (int j = 0; j < NCLS; j++) {
                th[i] += conf[i * NCLS + j];
                ph[j] += conf[i * NCLS + j];
            }
        double num = 0.0, den = 0.0;
        for (int i = 0; i < NCLS; i++)
            for (int j = 0; j < NCLS; j++) {
                double w = (double)((i - j) * (i - j)) / 16.0;  // (C-1)^2 = 16
                num += w * conf[i * NCLS + j];
                den += w * th[i] * ph[j];
            }
        out[0] = (float)(num * tot / den);   // (num/tot)/(den/tot^2)
    }
}

extern "C" void kernel_launch(void* const* d_in, const int* in_sizes, int n_in,
                              void* d_out, int out_size, void* d_ws, size_t ws_size,
                              hipStream_t stream) {
    const float* preds = (const float*)d_in[0];
    const int* truev = (const int*)d_in[1];
    const int N = in_sizes[1];  // number of samples (true is [N])

    int nblocks = NBLOCKS;
    size_t need = (size_t)nblocks * NBINS * sizeof(unsigned int);
    if (need > ws_size) nblocks = (int)(ws_size / (NBINS * sizeof(unsigned int)));
    unsigned int* partials = (unsigned int*)d_ws;

    kappa_count<<<nblocks, NTHREADS, 0, stream>>>(preds, truev, N, partials);
    kappa_final<<<1, 256, 0, stream>>>(partials, nblocks, (float*)d_out);
}

// Round 2
// 259.514 us; speedup vs baseline: 1.1613x; 1.1613x over previous
//
#include <hip/hip_runtime.h>
#include <math.h>

#define NCLS 5
#define NBINS 25
#define NTHREADS 256
#define NBLOCKS 4096

// Kernel 1: direct strided streaming, depth-2 software pipeline.
// Each thread owns 4 contiguous rows (80B = 5 x float4, 16B-aligned) per
// grid-stride step. Next step's 6 loads are issued BEFORE computing the
// current step, so each wave keeps ~12KB in flight through the compute
// phase. 4096 blocks @ launch_bounds(256,4) -> 16 waves/CU of TLP.
// Per-wave LDS histogram copies (no cross-wave atomic contention).
__global__ void __launch_bounds__(NTHREADS, 4)
kappa_count(const float* __restrict__ preds,
            const int* __restrict__ truev,
            int N,
            unsigned int* __restrict__ partials) {
    __shared__ unsigned int s_conf[4 * 32];   // per-wave histogram copies
    const int tid = threadIdx.x;
    const int wv = tid >> 6;
    if (tid < 128) s_conf[tid] = 0u;
    __syncthreads();
    unsigned int* hist = &s_conf[wv << 5];

    auto dorow = [&](float r0, float r1, float r2, float r3, float r4, int t) {
        // arithmetic kept expression-identical to the round-0 verified kernel
        float m = fmaxf(fmaxf(fmaxf(fmaxf(r0, r1), r2), r3), r4);
        float e0 = __expf(r0 - m), e1 = __expf(r1 - m), e2 = __expf(r2 - m),
              e3 = __expf(r3 - m), e4 = __expf(r4 - m);
        float s = e0 + e1 + e2 + e3 + e4;
        float dot = e1 + e2 * 2.f + e3 * 3.f + e4 * 4.f;
        int pi = (int)rintf(dot / s);          // round-half-even == jnp.round
        pi = min(max(pi, 0), NCLS - 1);
        atomicAdd(&hist[t * NCLS + pi], 1u);
    };

    const int nquad = N >> 2;
    const int gs = gridDim.x * blockDim.x;

    int q = blockIdx.x * blockDim.x + tid;
    if (q < nquad) {
        const float4* p4 = (const float4*)preds + (size_t)q * 5u;
        float4 a = p4[0], b = p4[1], c = p4[2], d = p4[3], e = p4[4];
        int4 t4 = *(const int4*)(truev + (size_t)q * 4u);
        for (;;) {
            const int qn = q + gs;
            const bool more = qn < nquad;
            float4 an, bn, cn, dn, en;
            int4 tn;
            if (more) {                        // prefetch next step (depth-2)
                const float4* pn = (const float4*)preds + (size_t)qn * 5u;
                an = pn[0]; bn = pn[1]; cn = pn[2]; dn = pn[3]; en = pn[4];
                tn = *(const int4*)(truev + (size_t)qn * 4u);
            }
            dorow(a.x, a.y, a.z, a.w, b.x, t4.x);
            dorow(b.y, b.z, b.w, c.x, c.y, t4.y);
            dorow(c.z, c.w, d.x, d.y, d.z, t4.z);
            dorow(d.w, e.x, e.y, e.z, e.w, t4.w);
            if (!more) break;
            a = an; b = bn; c = cn; d = dn; e = en; t4 = tn;
            q = qn;
        }
    }

    // Tail rows if N % 4 != 0 (N=8M divisible; kept for safety).
    if (blockIdx.x == 0 && tid < (N & 3)) {
        const int i = (N & ~3) + tid;
        float v[NCLS];
        #pragma unroll
        for (int j = 0; j < NCLS; j++) v[j] = preds[(size_t)i * NCLS + j];
        dorow(v[0], v[1], v[2], v[3], v[4], truev[i]);
    }

    __syncthreads();
    // bin-major (transposed) partials: partials[bin][block]
    if (tid < NBINS) {
        unsigned int v = s_conf[tid] + s_conf[32 + tid] +
                         s_conf[64 + tid] + s_conf[96 + tid];
        partials[(size_t)tid * gridDim.x + blockIdx.x] = v;
    }
}

// Kernel 2: bin-major reduction. 32 consecutive lanes per bin (25*32=800
// threads active of 1024), coalesced 128B reads per bin-group, shuffle
// reduce within the 32-lane subgroup, then O(25) kappa math in double.
__global__ void kappa_final(const unsigned int* __restrict__ partials,
                            int nb,
                            float* __restrict__ out) {
    __shared__ double s_bin[NBINS];
    const int tid = threadIdx.x;
    const int bin = tid >> 5;
    const int l = tid & 31;

    if (bin < NBINS) {
        unsigned int acc = 0u;                 // total count 8M fits u32
        const unsigned int* p = partials + (size_t)bin * nb;
        for (int j = l; j < nb; j += 32) acc += p[j];
        #pragma unroll
        for (int off = 16; off > 0; off >>= 1)
            acc += __shfl_down(acc, off, 32);
        if (l == 0) s_bin[bin] = (double)acc;
    }
    __syncthreads();

    if (tid == 0) {
        double tot = 0.0;
        for (int i = 0; i < NBINS; i++) tot += s_bin[i];
        double th[NCLS] = {0, 0, 0, 0, 0};
        double ph[NCLS] = {0, 0, 0, 0, 0};
        for (int i = 0; i < NCLS; i++)
            for (int j = 0; j < NCLS; j++) {
                th[i] += s_bin[i * NCLS + j];
                ph[j] += s_bin[i * NCLS + j];
            }
        double num = 0.0, den = 0.0;
        for (int i = 0; i < NCLS; i++)
            for (int j = 0; j < NCLS; j++) {
                double w = (double)((i - j) * (i - j)) / 16.0;  // (C-1)^2 = 16
                num += w * s_bin[i * NCLS + j];
                den += w * th[i] * ph[j];
            }
        out[0] = (float)(num * tot / den);     // (num/tot)/(den/tot^2)
    }
}

extern "C" void kernel_launch(void* const* d_in, const int* in_sizes, int n_in,
                              void* d_out, int out_size, void* d_ws, size_t ws_size,
                              hipStream_t stream) {
    const float* preds = (const float*)d_in[0];
    const int* truev = (const int*)d_in[1];
    const int N = in_sizes[1];  // number of samples (true is [N])

    int nblocks = NBLOCKS;
    size_t need = (size_t)nblocks * NBINS * sizeof(unsigned int);
    if (need > ws_size) nblocks = (int)(ws_size / (NBINS * sizeof(unsigned int)));
    unsigned int* partials = (unsigned int*)d_ws;

    kappa_count<<<nblocks, NTHREADS, 0, stream>>>(preds, truev, N, partials);
    kappa_final<<<1, 1024, 0, stream>>>(partials, nblocks, (float*)d_out);
}

// Round 3
// 246.494 us; speedup vs baseline: 1.2226x; 1.0528x over previous
//
#include <hip/hip_runtime.h>
#include <math.h>

#define NCLS 5
#define NBINS 25
#define NTHREADS 256
#define NBLOCKS 768                      // 3 blocks/CU resident (48.5KB LDS each)
#define ROWS_PER_CHUNK 256               // per-WAVE chunk: 256 rows
#define CHUNK_PRED_F4 320                // 256*5 floats / 4
#define PRED_SEGS 5                      // 5 x 1024B coalesced gload_lds

// global -> LDS direct copy, 16B/lane. LDS dest = wave-uniform base
// (HW adds lane*16); global src is per-lane.
__device__ __forceinline__ void gload_lds16(const void* g, void* l) {
    __builtin_amdgcn_global_load_lds(
        (const __attribute__((address_space(1))) unsigned int*)(const unsigned int*)g,
        (__attribute__((address_space(3))) unsigned int*)(unsigned int*)l,
        16, 0, 0);
}

// Kernel 1: wave-private LDS-staged streaming, BARRIER-FREE double buffer.
// Why: the direct 80B-stride float4 pattern requests each 64B L1 line ~4x
// (transaction-rate ceiling ~2.6 TB/s, invariant to TLP — rounds 0/2).
// Each wave stages its own 256-row chunk with 6 coalesced 1KB gload_lds
// (every line requested exactly once), prefetches the next chunk, and
// only waits vmcnt(6) — prefetch stays in flight across compute. No
// __syncthreads in the loop (staging wave == consuming wave), fixing
// round-1's lockstep drain.
// LDS read pattern: row = lane + 64*rr -> float idx 5*lane + c,
// gcd(5,32)=1 -> conflict-free.
__global__ void __launch_bounds__(NTHREADS)
kappa_count(const float* __restrict__ preds,
            const int* __restrict__ truev,
            int N,
            unsigned int* __restrict__ partials) {
    __shared__ float s_pred[2][4][ROWS_PER_CHUNK * NCLS];  // 40 KiB
    __shared__ int   s_lab [2][4][ROWS_PER_CHUNK];         // 8 KiB
    __shared__ unsigned int s_conf[4 * 32];                // per-wave hists

    const int tid = threadIdx.x;
    const int wv = tid >> 6;
    const int lane = tid & 63;
    if (tid < 128) s_conf[tid] = 0u;
    __syncthreads();
    unsigned int* hist = &s_conf[wv << 5];

    const int nchunks = N / ROWS_PER_CHUNK;
    const int wgid = blockIdx.x * 4 + wv;      // global wave id
    const int wstride = gridDim.x * 4;

    auto stage = [&](int c, int b) {
        const float4* sp = (const float4*)preds + (size_t)c * CHUNK_PRED_F4;
        #pragma unroll
        for (int k = 0; k < PRED_SEGS; ++k)
            gload_lds16(sp + k * 64 + lane,            // per-lane 16B src
                        &s_pred[b][wv][k * 256]);      // uniform 1KB seg base
        const int4* sl = (const int4*)(truev + (size_t)c * ROWS_PER_CHUNK);
        gload_lds16(sl + lane, &s_lab[b][wv][0]);      // 1KB of labels
    };

    auto dorow = [&](float r0, float r1, float r2, float r3, float r4, int t) {
        // arithmetic kept expression-identical to the verified round-0 kernel
        float m = fmaxf(fmaxf(fmaxf(fmaxf(r0, r1), r2), r3), r4);
        float e0 = __expf(r0 - m), e1 = __expf(r1 - m), e2 = __expf(r2 - m),
              e3 = __expf(r3 - m), e4 = __expf(r4 - m);
        float s = e0 + e1 + e2 + e3 + e4;
        float dot = e1 + e2 * 2.f + e3 * 3.f + e4 * 4.f;
        int pi = (int)rintf(dot / s);          // round-half-even == jnp.round
        pi = min(max(pi, 0), NCLS - 1);
        atomicAdd(&hist[t * NCLS + pi], 1u);
    };

    int c = wgid, cur = 0;
    if (c < nchunks) stage(c, 0);
    for (; c < nchunks; c += wstride) {
        const int cn = c + wstride;
        if (cn < nchunks) {
            stage(cn, cur ^ 1);                // 6 more loads in flight
            asm volatile("s_waitcnt vmcnt(6)" ::: "memory");  // cur chunk ready
        } else {
            asm volatile("s_waitcnt vmcnt(0)" ::: "memory");
        }
        const float* bp = s_pred[cur][wv];
        const int* lp = s_lab[cur][wv];
        #pragma unroll
        for (int rr = 0; rr < 4; ++rr) {
            const int r = lane + (rr << 6);
            const float* rp = bp + r * NCLS;
            dorow(rp[0], rp[1], rp[2], rp[3], rp[4], lp[r]);
        }
        cur ^= 1;
    }

    // Tail rows (N % 256 != 0; N=8M divisible — kept for safety).
    if (blockIdx.x == 0 && wv == 0) {
        for (int r = nchunks * ROWS_PER_CHUNK + lane; r < N; r += 64) {
            float v0 = preds[(size_t)r * NCLS + 0];
            float v1 = preds[(size_t)r * NCLS + 1];
            float v2 = preds[(size_t)r * NCLS + 2];
            float v3 = preds[(size_t)r * NCLS + 3];
            float v4 = preds[(size_t)r * NCLS + 4];
            dorow(v0, v1, v2, v3, v4, truev[r]);
        }
    }

    __syncthreads();
    // bin-major (transposed) partials: partials[bin][block]
    if (tid < NBINS)
        partials[(size_t)tid * gridDim.x + blockIdx.x] =
            s_conf[tid] + s_conf[32 + tid] + s_conf[64 + tid] + s_conf[96 + tid];
}

// Kernel 2: bin-major reduction. 32 lanes per bin, coalesced reads,
// shuffle reduce, then O(25) kappa math in double.
__global__ void kappa_final(const unsigned int* __restrict__ partials,
                            int nb,
                            float* __restrict__ out) {
    __shared__ double s_bin[NBINS];
    const int tid = threadIdx.x;
    const int bin = tid >> 5;
    const int l = tid & 31;

    if (bin < NBINS) {
        unsigned int acc = 0u;                 // total 8M fits u32
        const unsigned int* p = partials + (size_t)bin * nb;
        for (int j = l; j < nb; j += 32) acc += p[j];
        #pragma unroll
        for (int off = 16; off > 0; off >>= 1)
            acc += __shfl_down(acc, off, 32);
        if (l == 0) s_bin[bin] = (double)acc;
    }
    __syncthreads();

    if (tid == 0) {
        double tot = 0.0;
        for (int i = 0; i < NBINS; i++) tot += s_bin[i];
        double th[NCLS] = {0, 0, 0, 0, 0};
        double ph[NCLS] = {0, 0, 0, 0, 0};
        for (int i = 0; i < NCLS; i++)
            for (int j = 0; j < NCLS; j++) {
                th[i] += s_bin[i * NCLS + j];
                ph[j] += s_bin[i * NCLS + j];
            }
        double num = 0.0, den = 0.0;
        for (int i = 0; i < NCLS; i++)
            for (int j = 0; j < NCLS; j++) {
                double w = (double)((i - j) * (i - j)) / 16.0;  // (C-1)^2 = 16
                num += w * s_bin[i * NCLS + j];
                den += w * th[i] * ph[j];
            }
        out[0] = (float)(num * tot / den);     // (num/tot)/(den/tot^2)
    }
}

extern "C" void kernel_launch(void* const* d_in, const int* in_sizes, int n_in,
                              void* d_out, int out_size, void* d_ws, size_t ws_size,
                              hipStream_t stream) {
    const float* preds = (const float*)d_in[0];
    const int* truev = (const int*)d_in[1];
    const int N = in_sizes[1];  // number of samples (true is [N])

    int nblocks = NBLOCKS;
    size_t need = (size_t)nblocks * NBINS * sizeof(unsigned int);
    if (need > ws_size) nblocks = (int)(ws_size / (NBINS * sizeof(unsigned int)));
    unsigned int* partials = (unsigned int*)d_ws;

    kappa_count<<<nblocks, NTHREADS, 0, stream>>>(preds, truev, N, partials);
    kappa_final<<<1, 1024, 0, stream>>>(partials, nblocks, (float*)d_out);
}